// Round 5
// baseline (111.925 us; speedup 1.0000x reference)
//
#include <hip/hip_runtime.h>
#include <math.h>

#define NB 256
#define NV 6890
#define NF 13776
#define NHD 20000
#define NHDP 20480            // NHD padded to 20 * 1024
#define NPARTS 10
#define PY 120
#define PX 40
#define THREADS 1024
#define NWAVES (THREADS / 64)

// d_ws layout (bytes):
//   [0, 1024)      : per-batch distances (NB floats)
//   [1024, 1028)   : completion counter (zeroed by build_tabs)
//   [2048, +NF*16) : face table   int4{i0,i1,i2,part}
//   [.., +NHDP*16) : sample table int4{i0,i1,i2,part}   (pads: {0,0,0,0})
//   [.., +NHDP*16) : sample bary  float4{w0,w1,w2,mask} (pads: mask=0)
#define WS_DIST_OFF  0
#define WS_CTR_OFF   1024
#define WS_TABF_OFF  2048
#define WS_TABS_OFF  (WS_TABF_OFF + NF * 16)
#define WS_TABW_OFF  (WS_TABS_OFF + NHDP * 16)
#define WS_NEEDED    (WS_TABW_OFF + NHDP * 16)

__device__ __forceinline__ float wred(float v) {
#pragma unroll
    for (int off = 32; off; off >>= 1) v += __shfl_down(v, off, 64);
    return v;
}

__global__ __launch_bounds__(256) void build_tabs(const int* __restrict__ faces,
                                                  const int* __restrict__ face_part,
                                                  const int* __restrict__ face_sample,
                                                  const float* __restrict__ bary_w,
                                                  int4* __restrict__ tabF,
                                                  int4* __restrict__ tabS,
                                                  float4* __restrict__ tabW,
                                                  unsigned int* __restrict__ ctr) {
    const int i = blockIdx.x * 256 + threadIdx.x;
    if (i == 0) *ctr = 0u;   // reset completion counter every call
    if (i < NF)
        tabF[i] = make_int4(faces[3 * i + 0], faces[3 * i + 1], faces[3 * i + 2], face_part[i]);
    if (i < NHD) {
        const int fs = face_sample[i];
        tabS[i] = make_int4(faces[3 * fs + 0], faces[3 * fs + 1], faces[3 * fs + 2], face_part[fs]);
        tabW[i] = make_float4(bary_w[3 * i + 0], bary_w[3 * i + 1], bary_w[3 * i + 2], 1.0f);
    } else if (i < NHDP) {
        tabS[i] = make_int4(0, 0, 0, 0);
        tabW[i] = make_float4(0.0f, 0.0f, 0.0f, 0.0f);
    }
}

__device__ __forceinline__ float tet_of(const float* __restrict__ svx,
                                        const float* __restrict__ svy,
                                        const float* __restrict__ svz, int4 q) {
    const float ax = svx[q.x], bx = svx[q.y], cx = svx[q.z];
    const float ay = svy[q.x], by = svy[q.y], cy = svy[q.z];
    const float az = svz[q.x], bz = svz[q.y], cz = svz[q.z];
    return (ax * (by * cz - bz * cy) + ay * (bz * cx - bx * cz) + az * (bx * cy - by * cx)) *
           (1.0f / 6.0f);
}

template <bool TAB>
__global__ __launch_bounds__(THREADS, 4) void stab_main(
    const float* __restrict__ vertices,    // [NB, NV, 3]
    const float* __restrict__ pressure,    // [NB, PY, PX]
    const float* __restrict__ bary_w,      // [NHD, 3]
    const int*   __restrict__ faces,       // [NF, 3]
    const int*   __restrict__ face_sample, // [NHD]
    const int*   __restrict__ face_part,   // [NF]
    const int4*  __restrict__ tabF,
    const int4*  __restrict__ tabS,
    const float4* __restrict__ tabW,
    float* __restrict__ out,
    float* __restrict__ dist,
    unsigned int* __restrict__ ctr)
{
    const int b    = blockIdx.x;
    const int tid  = threadIdx.x;
    const int wave = tid >> 6;
    const int lane = tid & 63;
    const int ln32 = tid & 31;

    __shared__ float svx[NV];
    __shared__ float svy[NV];
    __shared__ float svz[NV];
    __shared__ float red[NWAVES][12];
    __shared__ float ppvR[NPARTS * 32];   // replicated per 32-lane group: conflict-free
    __shared__ int   slast;

    // ---- stage vertices[b] into LDS (f32 SoA) ----
    const float* vb = vertices + (size_t)b * (NV * 3);
    for (int v = tid; v < NV; v += THREADS) {
        svx[v] = vb[3 * v + 0];
        svy[v] = vb[3 * v + 1];
        svz[v] = vb[3 * v + 2];
    }
    __syncthreads();

    // ---- Phase A: tet volumes -> per-part sums (4 independent chains / iter) ----
    float pv[NPARTS];
#pragma unroll
    for (int p = 0; p < NPARTS; ++p) pv[p] = 0.0f;

    if constexpr (TAB) {
        for (int f0 = tid; f0 < NF; f0 += 4 * THREADS) {
            const int f1 = f0 + THREADS, f2 = f0 + 2 * THREADS, f3 = f0 + 3 * THREADS;
            const int g1 = min(f1, NF - 1), g2 = min(f2, NF - 1), g3 = min(f3, NF - 1);
            const int4 q0 = tabF[f0];
            const int4 q1 = tabF[g1];
            const int4 q2 = tabF[g2];
            const int4 q3 = tabF[g3];
            const float m1 = (f1 < NF) ? 1.0f : 0.0f;
            const float m2 = (f2 < NF) ? 1.0f : 0.0f;
            const float m3 = (f3 < NF) ? 1.0f : 0.0f;
            const float t0 = tet_of(svx, svy, svz, q0);
            const float t1 = tet_of(svx, svy, svz, q1) * m1;
            const float t2 = tet_of(svx, svy, svz, q2) * m2;
            const float t3 = tet_of(svx, svy, svz, q3) * m3;
#pragma unroll
            for (int p = 0; p < NPARTS; ++p) {
                pv[p] += (q0.w == p) ? t0 : 0.0f;
                pv[p] += (q1.w == p) ? t1 : 0.0f;
                pv[p] += (q2.w == p) ? t2 : 0.0f;
                pv[p] += (q3.w == p) ? t3 : 0.0f;
            }
        }
    } else {
        for (int f = tid; f < NF; f += THREADS) {
            const int4 q = make_int4(faces[3 * f + 0], faces[3 * f + 1], faces[3 * f + 2],
                                     face_part[f]);
            const float t = tet_of(svx, svy, svz, q);
#pragma unroll
            for (int p = 0; p < NPARTS; ++p) pv[p] += (q.w == p) ? t : 0.0f;
        }
    }
#pragma unroll
    for (int p = 0; p < NPARTS; ++p) {
        const float r = wred(pv[p]);
        if (lane == 0) red[wave][p] = r;
    }
    __syncthreads();
    if (tid < NPARTS * 32) {
        const int p = tid >> 5;
        float s = 0.0f;
#pragma unroll
        for (int w = 0; w < NWAVES; ++w) s += red[w][p];
        ppvR[tid] = s;
    }
    __syncthreads();

    // ---- Phase B: blended samples, software-pipelined table reads ----
    float cnx = 0.f, cny = 0.f, cd = 0.f;
    float pnx = 0.f, pny = 0.f, pd = 0.f;

#define PROC_B()                                                                     \
    _Pragma("unroll")                                                                \
    for (int u = 0; u < 4; ++u) {                                                    \
        const int4 q = qc[u];                                                        \
        const float4 w = wc[u];                                                      \
        const float hx = w.x * svx[q.x] + w.y * svx[q.y] + w.z * svx[q.z];           \
        const float hy = w.x * svy[q.x] + w.y * svy[q.y] + w.z * svy[q.z];           \
        const float vol = ppvR[(q.w << 5) + ln32] * w.w;                             \
        const float pw = ((hy < 0.0f) ? (1.0f - 100.0f * hy) : __expf(-10.0f * hy))  \
                         * w.w;                                                      \
        cnx += hx * vol; cny += hy * vol; cd += vol;                                 \
        pnx += hx * pw;  pny += hy * pw;  pd += pw;                                  \
    }

    if constexpr (TAB) {
        int4   qc[4];
        float4 wc[4];
#pragma unroll
        for (int u = 0; u < 4; ++u) {
            qc[u] = tabS[tid + u * THREADS];
            wc[u] = tabW[tid + u * THREADS];
        }
        for (int g = 0; g < 4; ++g) {          // prefetch g+1 while processing g
            int4   qn[4];
            float4 wn[4];
            const int base = tid + 4 * (g + 1) * THREADS;
#pragma unroll
            for (int u = 0; u < 4; ++u) {
                qn[u] = tabS[base + u * THREADS];
                wn[u] = tabW[base + u * THREADS];
            }
            PROC_B();
#pragma unroll
            for (int u = 0; u < 4; ++u) { qc[u] = qn[u]; wc[u] = wn[u]; }
        }
        PROC_B();                              // tail group (g = 4)
    } else {
        for (int n = tid; n < NHD; n += THREADS) {
            const int fs = face_sample[n];
            const int i0 = faces[3 * fs + 0], i1 = faces[3 * fs + 1], i2 = faces[3 * fs + 2];
            const float w0 = bary_w[3 * n + 0], w1 = bary_w[3 * n + 1], w2 = bary_w[3 * n + 2];
            const float hx = w0 * svx[i0] + w1 * svx[i1] + w2 * svx[i2];
            const float hy = w0 * svy[i0] + w1 * svy[i1] + w2 * svy[i2];
            const float vol = ppvR[(face_part[fs] << 5) + ln32];
            cnx += hx * vol; cny += hy * vol; cd += vol;
            const float pw = (hy < 0.0f) ? (1.0f - 100.0f * hy) : __expf(-10.0f * hy);
            pnx += hx * pw; pny += hy * pw; pd += pw;
        }
    }
#undef PROC_B

    // ---- pressure moments (float4) ----
    float pt = 0.f, pxs = 0.f, pys = 0.f;
    const float4* pb4 = (const float4*)(pressure + (size_t)b * (PY * PX));
    for (int i = tid; i < (PY * PX) / 4; i += THREADS) {
        const float4 v = pb4[i];
        const int idx = 4 * i;
        const float xb = (float)(idx % PX);
        const float yb = (float)(idx / PX);
        const float srow = v.x + v.y + v.z + v.w;
        pt  += srow;
        pxs += v.x * xb + v.y * (xb + 1.0f) + v.z * (xb + 2.0f) + v.w * (xb + 3.0f);
        pys += srow * yb;
    }

    // ---- block reduction of 9 scalars ----
    float vals[9] = {cnx, cny, cd, pnx, pny, pd, pt, pxs, pys};
#pragma unroll
    for (int k = 0; k < 9; ++k) {
        const float r = wred(vals[k]);
        if (lane == 0) red[wave][k] = r;
    }
    __syncthreads();

    if (tid == 0) {
        float s[9];
#pragma unroll
        for (int k = 0; k < 9; ++k) {
            float acc = 0.0f;
#pragma unroll
            for (int w = 0; w < NWAVES; ++w) acc += red[w][k];
            s[k] = acc;
        }
        const float comx  = s[0] / s[2];
        const float comy  = s[1] / s[2];
        const float copx  = s[3] / (s[5] + 1e-6f);
        const float copy_ = s[4] / (s[5] + 1e-6f);

        out[1 + 2 * b + 0] = comx * 48.0f;
        out[1 + 2 * b + 1] = (59.0f / 33.0f - comy) * 33.0f;
        out[1 + 2 * NB + 2 * b + 0] = (copx + 18.0f / 78.74f) * (100.0f * 0.7874f);
        out[1 + 2 * NB + 2 * b + 1] = (86.0f / 78.74f - copy_) * (100.0f * 0.7874f);

        const float total = (s[6] == 0.0f) ? 1e-8f : s[6];
        const float xc = s[7] / total;
        const float yc = s[8] / total;
        const float pcopx = 0.01f * (xc - 18.0f) / 0.7874f;
        const float pcopy = 0.01f * (86.0f - yc) / 0.7874f;

        const float dx = comx - pcopx;
        const float dy = comy - pcopy;
        dist[b] = sqrtf(dx * dx + dy * dy);
    }

    // ---- fused final reduce: last block to finish sums dist[] ----
    if constexpr (TAB) {
        if (tid == 0) {
            __threadfence();                       // make dist[b] visible device-wide
            const unsigned int prev = atomicAdd(ctr, 1u);
            slast = (prev == NB - 1) ? 1 : 0;
        }
        __syncthreads();
        if (slast) {
            __threadfence();
            float v = 0.0f;
            if (tid < NB)
                v = __hip_atomic_load(&dist[tid], __ATOMIC_RELAXED,
                                      __HIP_MEMORY_SCOPE_AGENT);  // bypass stale L2
            v = wred(v);
            if (lane == 0) red[wave][0] = v;
            __syncthreads();
            if (tid == 0) {
                float s = 0.0f;
#pragma unroll
                for (int w = 0; w < 4; ++w) s += red[w][0];  // only waves 0-3 hold dist
                out[0] = s * (1.0f / NB);
            }
        }
    }
}

__global__ __launch_bounds__(256) void stab_reduce(const float* __restrict__ dist,
                                                   float* __restrict__ out) {
    const int tid = threadIdx.x;
    float v = dist[tid];
    v = wred(v);
    __shared__ float red[4];
    if ((tid & 63) == 0) red[tid >> 6] = v;
    __syncthreads();
    if (tid == 0) out[0] = (red[0] + red[1] + red[2] + red[3]) * (1.0f / 256.0f);
}

extern "C" void kernel_launch(void* const* d_in, const int* in_sizes, int n_in,
                              void* d_out, int out_size, void* d_ws, size_t ws_size,
                              hipStream_t stream) {
    const float* vertices    = (const float*)d_in[0];
    const float* pressure    = (const float*)d_in[1];
    const float* bary_w      = (const float*)d_in[2];
    const int*   faces       = (const int*)d_in[3];
    const int*   face_sample = (const int*)d_in[4];
    const int*   face_part   = (const int*)d_in[5];
    float* out = (float*)d_out;
    char*  ws  = (char*)d_ws;

    float* dist        = (float*)(ws + WS_DIST_OFF);
    unsigned int* ctr  = (unsigned int*)(ws + WS_CTR_OFF);

    if (ws_size >= (size_t)WS_NEEDED) {
        int4*   tabF = (int4*)(ws + WS_TABF_OFF);
        int4*   tabS = (int4*)(ws + WS_TABS_OFF);
        float4* tabW = (float4*)(ws + WS_TABW_OFF);
        build_tabs<<<(NHDP + 255) / 256, 256, 0, stream>>>(faces, face_part, face_sample,
                                                           bary_w, tabF, tabS, tabW, ctr);
        stab_main<true><<<NB, THREADS, 0, stream>>>(vertices, pressure, bary_w, faces,
                                                    face_sample, face_part, tabF, tabS, tabW,
                                                    out, dist, ctr);
    } else {
        stab_main<false><<<NB, THREADS, 0, stream>>>(vertices, pressure, bary_w, faces,
                                                     face_sample, face_part, nullptr, nullptr,
                                                     nullptr, out, dist, ctr);
        stab_reduce<<<1, 256, 0, stream>>>(dist, out);
    }
}

// Round 6
// 79.353 us; speedup vs baseline: 1.4105x; 1.4105x over previous
//
#include <hip/hip_runtime.h>
#include <math.h>

#define NB 256
#define NV 6890
#define VL 6656                 // vertices resident in LDS (raw xyz, 79872 B)
#define NF 13776
#define NFH (NF / 2)            // 6888 faces per half-block
#define NHD 20000
#define NHDP 21504              // padded to 2 * 768 * 14
#define NHDH (NHDP / 2)         // 10752 samples per half-block
#define NPARTS 10
#define PY 120
#define PX 40
#define TA 768
#define NWA (TA / 64)           // 12 waves

// ws float-index layout:
//   [256 .. )        pA[13][512]  : per (batch,half): pv[0..9], pt, pxs, pys
//   [PB_OFF .. )     pB[6][512]   : per (batch,half): cnx,cny,cd,pnx,pny,pd
// byte layout after scalars (16B aligned):
#define PA_OFF 256
#define PB_OFF (PA_OFF + 13 * 512)
#define TABS_BYTE ((PB_OFF + 6 * 512) * 4)      // 39936, %16 == 0
#define TABW_BYTE (TABS_BYTE + NHDP * 16)
#define WS_NEEDED (TABW_BYTE + NHDP * 16)

__device__ __forceinline__ float wred(float v) {
#pragma unroll
    for (int off = 32; off; off >>= 1) v += __shfl_down(v, off, 64);
    return v;
}

// ---- batch-independent gather tables (rebuilt every call: deterministic) ----
__global__ __launch_bounds__(256) void build_tabs(const int* __restrict__ faces,
                                                  const int* __restrict__ face_sample,
                                                  const int* __restrict__ face_part,
                                                  const float* __restrict__ bary_w,
                                                  int4* __restrict__ tabS,
                                                  float4* __restrict__ tabW) {
    const int i = blockIdx.x * 256 + threadIdx.x;
    if (i < NHD) {
        const int fs = face_sample[i];
        tabS[i] = make_int4(faces[3 * fs + 0], faces[3 * fs + 1], faces[3 * fs + 2],
                            face_part[fs]);
        tabW[i] = make_float4(bary_w[3 * i + 0], bary_w[3 * i + 1], bary_w[3 * i + 2], 1.0f);
    } else if (i < NHDP) {
        tabS[i] = make_int4(0, 0, 0, 0);
        tabW[i] = make_float4(0.0f, 0.0f, 0.0f, 0.0f);   // mask=0 pad
    }
}

// ---- kA: per-part tet volumes (half the faces) + half the pressure grid ----
__global__ __launch_bounds__(TA, 6) void kA(const float* __restrict__ vertices,
                                            const float* __restrict__ pressure,
                                            const int*   __restrict__ faces,
                                            const int*   __restrict__ face_part,
                                            float* __restrict__ pA) {
    const int bid  = blockIdx.x;
    const int b    = bid >> 1;
    const int half = bid & 1;
    const int tid  = threadIdx.x;
    const int wave = tid >> 6;
    const int lane = tid & 63;

    __shared__ float sv[VL * 3];          // raw xyz, 79872 B
    __shared__ float red[NWA][13];

    const float*  vb  = vertices + (size_t)b * (NV * 3);
    const float2* vb2 = (const float2*)vb;                 // 8B aligned for every b
    for (int i = tid; i < (VL * 3) / 2; i += TA) ((float2*)sv)[i] = vb2[i];
    __syncthreads();

    float pv[NPARTS];
#pragma unroll
    for (int p = 0; p < NPARTS; ++p) pv[p] = 0.0f;

    const int fbase = half * NFH;
    for (int i = tid; i < NFH; i += TA) {
        const int f  = fbase + i;
        const int i0 = faces[3 * f + 0];
        const int i1 = faces[3 * f + 1];
        const int i2 = faces[3 * f + 2];
        const int part = face_part[f];
        float ax, ay, az, bx, by, bz, cx, cy, cz;
        if (i0 < VL) { ax = sv[3 * i0]; ay = sv[3 * i0 + 1]; az = sv[3 * i0 + 2]; }
        else         { ax = vb[3 * i0]; ay = vb[3 * i0 + 1]; az = vb[3 * i0 + 2]; }
        if (i1 < VL) { bx = sv[3 * i1]; by = sv[3 * i1 + 1]; bz = sv[3 * i1 + 2]; }
        else         { bx = vb[3 * i1]; by = vb[3 * i1 + 1]; bz = vb[3 * i1 + 2]; }
        if (i2 < VL) { cx = sv[3 * i2]; cy = sv[3 * i2 + 1]; cz = sv[3 * i2 + 2]; }
        else         { cx = vb[3 * i2]; cy = vb[3 * i2 + 1]; cz = vb[3 * i2 + 2]; }
        const float t = (ax * (by * cz - bz * cy) +
                         ay * (bz * cx - bx * cz) +
                         az * (bx * cy - by * cx)) * (1.0f / 6.0f);
#pragma unroll
        for (int p = 0; p < NPARTS; ++p) pv[p] += (part == p) ? t : 0.0f;
    }

    // pressure moments, this block's half (600 float4 groups)
    float pt = 0.f, pxs = 0.f, pys = 0.f;
    const float4* pb4 = (const float4*)(pressure + (size_t)b * (PY * PX));
    for (int i = tid; i < 600; i += TA) {
        const int i4 = half * 600 + i;
        const float4 v = pb4[i4];
        const int idx = 4 * i4;
        const float xb = (float)(idx % PX);
        const float yb = (float)(idx / PX);
        const float srow = v.x + v.y + v.z + v.w;
        pt  += srow;
        pxs += v.x * xb + v.y * (xb + 1.0f) + v.z * (xb + 2.0f) + v.w * (xb + 3.0f);
        pys += srow * yb;
    }

    float vals[13] = {pv[0], pv[1], pv[2], pv[3], pv[4], pv[5], pv[6], pv[7], pv[8], pv[9],
                      pt, pxs, pys};
#pragma unroll
    for (int k = 0; k < 13; ++k) {
        const float r = wred(vals[k]);
        if (lane == 0) red[wave][k] = r;
    }
    __syncthreads();
    if (tid < 13) {
        float s = 0.0f;
#pragma unroll
        for (int w = 0; w < NWA; ++w) s += red[w][tid];
        pA[tid * 512 + bid] = s;
    }
}

// ---- kB: blended samples (half), COM via combined ppv + weighted CoP ----
__global__ __launch_bounds__(TA, 6) void kB(const float* __restrict__ vertices,
                                            const int4*  __restrict__ tabS,
                                            const float4* __restrict__ tabW,
                                            const float* __restrict__ pA,
                                            float* __restrict__ pB) {
    const int bid  = blockIdx.x;
    const int b    = bid >> 1;
    const int half = bid & 1;
    const int tid  = threadIdx.x;
    const int wave = tid >> 6;
    const int lane = tid & 63;
    const int ln32 = tid & 31;

    __shared__ float sv[VL * 3];          // 79872 B
    __shared__ float red[NWA][6];
    __shared__ float ppvR[NPARTS * 32];   // 1280 B, replicated: conflict-free

    const float*  vb  = vertices + (size_t)b * (NV * 3);
    const float2* vb2 = (const float2*)vb;
    for (int i = tid; i < (VL * 3) / 2; i += TA) ((float2*)sv)[i] = vb2[i];
    if (tid < NPARTS * 32) {
        const int p = tid >> 5;
        ppvR[tid] = pA[p * 512 + 2 * b] + pA[p * 512 + 2 * b + 1];   // combine halves
    }
    __syncthreads();

    float cnx = 0.f, cny = 0.f, cd = 0.f;
    float pnx = 0.f, pny = 0.f, pd = 0.f;

    const int nbase = half * NHDH;
#pragma unroll 2
    for (int i = tid; i < NHDH; i += TA) {        // 14 exact iterations
        const int n = nbase + i;
        const int4   q = tabS[n];
        const float4 w = tabW[n];
        float x0, y0, x1, y1, x2, y2;
        if (q.x < VL) { x0 = sv[3 * q.x]; y0 = sv[3 * q.x + 1]; }
        else          { x0 = vb[3 * q.x]; y0 = vb[3 * q.x + 1]; }
        if (q.y < VL) { x1 = sv[3 * q.y]; y1 = sv[3 * q.y + 1]; }
        else          { x1 = vb[3 * q.y]; y1 = vb[3 * q.y + 1]; }
        if (q.z < VL) { x2 = sv[3 * q.z]; y2 = sv[3 * q.z + 1]; }
        else          { x2 = vb[3 * q.z]; y2 = vb[3 * q.z + 1]; }
        const float hx = w.x * x0 + w.y * x1 + w.z * x2;
        const float hy = w.x * y0 + w.y * y1 + w.z * y2;
        const float vol = ppvR[(q.w << 5) + ln32] * w.w;
        const float pw  = ((hy < 0.0f) ? (1.0f - 100.0f * hy) : __expf(-10.0f * hy)) * w.w;
        cnx += hx * vol; cny += hy * vol; cd += vol;
        pnx += hx * pw;  pny += hy * pw;  pd += pw;
    }

    float vals[6] = {cnx, cny, cd, pnx, pny, pd};
#pragma unroll
    for (int k = 0; k < 6; ++k) {
        const float r = wred(vals[k]);
        if (lane == 0) red[wave][k] = r;
    }
    __syncthreads();
    if (tid < 6) {
        float s = 0.0f;
#pragma unroll
        for (int w = 0; w < NWA; ++w) s += red[w][tid];
        pB[tid * 512 + bid] = s;
    }
}

// ---- kC: combine halves, final math, outputs + stability mean ----
__global__ __launch_bounds__(256) void kC(const float* __restrict__ pA,
                                          const float* __restrict__ pB,
                                          float* __restrict__ out) {
    const int b    = threadIdx.x;
    const int wave = b >> 6;
    const int lane = b & 63;
    __shared__ float red[4];

    const float cnx = pB[0 * 512 + 2 * b] + pB[0 * 512 + 2 * b + 1];
    const float cny = pB[1 * 512 + 2 * b] + pB[1 * 512 + 2 * b + 1];
    const float cd  = pB[2 * 512 + 2 * b] + pB[2 * 512 + 2 * b + 1];
    const float pnx = pB[3 * 512 + 2 * b] + pB[3 * 512 + 2 * b + 1];
    const float pny = pB[4 * 512 + 2 * b] + pB[4 * 512 + 2 * b + 1];
    const float pd  = pB[5 * 512 + 2 * b] + pB[5 * 512 + 2 * b + 1];
    const float pt  = pA[10 * 512 + 2 * b] + pA[10 * 512 + 2 * b + 1];
    const float pxs = pA[11 * 512 + 2 * b] + pA[11 * 512 + 2 * b + 1];
    const float pys = pA[12 * 512 + 2 * b] + pA[12 * 512 + 2 * b + 1];

    const float comx  = cnx / cd;
    const float comy  = cny / cd;
    const float copx  = pnx / (pd + 1e-6f);
    const float copy_ = pny / (pd + 1e-6f);

    out[1 + 2 * b + 0] = comx * 48.0f;
    out[1 + 2 * b + 1] = (59.0f / 33.0f - comy) * 33.0f;
    out[1 + 2 * NB + 2 * b + 0] = (copx + 18.0f / 78.74f) * (100.0f * 0.7874f);
    out[1 + 2 * NB + 2 * b + 1] = (86.0f / 78.74f - copy_) * (100.0f * 0.7874f);

    const float total = (pt == 0.0f) ? 1e-8f : pt;
    const float xc = pxs / total;
    const float yc = pys / total;
    const float pcopx = 0.01f * (xc - 18.0f) / 0.7874f;
    const float pcopy = 0.01f * (86.0f - yc) / 0.7874f;

    const float dx = comx - pcopx;
    const float dy = comy - pcopy;
    float v = sqrtf(dx * dx + dy * dy);

    v = wred(v);
    if (lane == 0) red[wave] = v;
    __syncthreads();
    if (b == 0) out[0] = (red[0] + red[1] + red[2] + red[3]) * (1.0f / NB);
}

extern "C" void kernel_launch(void* const* d_in, const int* in_sizes, int n_in,
                              void* d_out, int out_size, void* d_ws, size_t ws_size,
                              hipStream_t stream) {
    const float* vertices    = (const float*)d_in[0];
    const float* pressure    = (const float*)d_in[1];
    const float* bary_w      = (const float*)d_in[2];
    const int*   faces       = (const int*)d_in[3];
    const int*   face_sample = (const int*)d_in[4];
    const int*   face_part   = (const int*)d_in[5];
    float* out  = (float*)d_out;
    char*  wsb  = (char*)d_ws;
    float* wsf  = (float*)d_ws;

    float*  pA   = wsf + PA_OFF;
    float*  pB   = wsf + PB_OFF;
    int4*   tabS = (int4*)(wsb + TABS_BYTE);
    float4* tabW = (float4*)(wsb + TABW_BYTE);

    build_tabs<<<(NHDP + 255) / 256, 256, 0, stream>>>(faces, face_sample, face_part,
                                                       bary_w, tabS, tabW);
    kA<<<NB * 2, TA, 0, stream>>>(vertices, pressure, faces, face_part, pA);
    kB<<<NB * 2, TA, 0, stream>>>(vertices, tabS, tabW, pA, pB);
    kC<<<1, 256, 0, stream>>>(pA, pB, out);
}

// Round 7
// 56.657 us; speedup vs baseline: 1.9755x; 1.4006x over previous
//
#include <hip/hip_runtime.h>
#include <math.h>

#define NB 256
#define NV 6890
#define NF 13776
#define NHD 20000
#define NHDP 20480              // padded: 2 halves x 1024 threads x 10 iters
#define NHDH 10240
#define NPARTS 10
#define PY 120
#define PX 40

// ws layout: ctr(uint) @0; pA[13][256] floats @64; pB[6][512] floats after;
// then tabS[NHDP] int4, tabW[NHDP] float4.
#define PA_OFF 64
#define PB_OFF (PA_OFF + 13 * 256)
#define TABS_BYTE ((PB_OFF + 6 * 512) * 4)          // 25856, %16==0
#define TABW_BYTE (TABS_BYTE + NHDP * 16)

__device__ __forceinline__ float wred(float v) {
#pragma unroll
    for (int off = 32; off; off >>= 1) v += __shfl_down(v, off, 64);
    return v;
}

// ---- batch-independent sample tables + ctr reset ----
__global__ __launch_bounds__(256) void build_tabs(const int* __restrict__ faces,
                                                  const int* __restrict__ face_sample,
                                                  const int* __restrict__ face_part,
                                                  const float* __restrict__ bary_w,
                                                  int4* __restrict__ tabS,
                                                  float4* __restrict__ tabW,
                                                  unsigned int* __restrict__ ctr) {
    const int i = blockIdx.x * 256 + threadIdx.x;
    if (i == 0) *ctr = 0u;
    if (i < NHD) {
        const int fs = face_sample[i];
        tabS[i] = make_int4(faces[3 * fs + 0], faces[3 * fs + 1], faces[3 * fs + 2],
                            face_part[fs]);
        tabW[i] = make_float4(bary_w[3 * i + 0], bary_w[3 * i + 1], bary_w[3 * i + 2], 1.0f);
    } else if (i < NHDP) {
        tabS[i] = make_int4(0, 0, 0, 0);
        tabW[i] = make_float4(0.0f, 0.0f, 0.0f, 0.0f);   // mask=0 pad
    }
}

// ---- kA: full xyz in LDS (1 blk/CU), per-part tet volumes + pressure ----
__global__ __launch_bounds__(1024, 4) void kA(const float* __restrict__ vertices,
                                              const float* __restrict__ pressure,
                                              const int*   __restrict__ faces,
                                              const int*   __restrict__ face_part,
                                              float* __restrict__ pA) {
    const int b    = blockIdx.x;
    const int tid  = threadIdx.x;
    const int wave = tid >> 6;
    const int lane = tid & 63;

    __shared__ float sv[NV * 3];          // 82680 B
    __shared__ float red[16][13];

    const float*  vb  = vertices + (size_t)b * (NV * 3);
    const float2* vb2 = (const float2*)vb;
    for (int i = tid; i < (NV * 3) / 2; i += 1024) ((float2*)sv)[i] = vb2[i];
    if (tid == 0) sv[NV * 3 - 1] = vb[NV * 3 - 1];   // odd tail element
    __syncthreads();

    float pv[NPARTS];
#pragma unroll
    for (int p = 0; p < NPARTS; ++p) pv[p] = 0.0f;

#define TET(F, T)                                                                  \
    {                                                                              \
        const int i0 = faces[3 * (F)], i1 = faces[3 * (F) + 1], i2 = faces[3 * (F) + 2]; \
        const float ax = sv[3 * i0], ay = sv[3 * i0 + 1], az = sv[3 * i0 + 2];     \
        const float bx = sv[3 * i1], by = sv[3 * i1 + 1], bz = sv[3 * i1 + 2];     \
        const float cx = sv[3 * i2], cy = sv[3 * i2 + 1], cz = sv[3 * i2 + 2];     \
        T = (ax * (by * cz - bz * cy) + ay * (bz * cx - bx * cz) +                 \
             az * (bx * cy - by * cx)) * (1.0f / 6.0f);                            \
    }

    for (int f0 = tid; f0 < NF; f0 += 4096) {
        const int f1 = f0 + 1024, f2 = f0 + 2048, f3 = f0 + 3072;
        const int g1 = min(f1, NF - 1), g2 = min(f2, NF - 1), g3 = min(f3, NF - 1);
        const int p0 = face_part[f0], p1 = face_part[g1];
        const int p2 = face_part[g2], p3 = face_part[g3];
        float t0, t1, t2, t3;
        TET(f0, t0);
        TET(g1, t1);
        TET(g2, t2);
        TET(g3, t3);
        t1 *= (f1 < NF) ? 1.0f : 0.0f;
        t2 *= (f2 < NF) ? 1.0f : 0.0f;
        t3 *= (f3 < NF) ? 1.0f : 0.0f;
#pragma unroll
        for (int p = 0; p < NPARTS; ++p) {
            pv[p] += (p0 == p) ? t0 : 0.0f;
            pv[p] += (p1 == p) ? t1 : 0.0f;
            pv[p] += (p2 == p) ? t2 : 0.0f;
            pv[p] += (p3 == p) ? t3 : 0.0f;
        }
    }
#undef TET

    // pressure moments
    float pt = 0.f, pxs = 0.f, pys = 0.f;
    const float4* pb4 = (const float4*)(pressure + (size_t)b * (PY * PX));
    for (int i = tid; i < (PY * PX) / 4; i += 1024) {
        const float4 v = pb4[i];
        const int idx = 4 * i;
        const float xb = (float)(idx % PX);
        const float yb = (float)(idx / PX);
        const float srow = v.x + v.y + v.z + v.w;
        pt  += srow;
        pxs += v.x * xb + v.y * (xb + 1.0f) + v.z * (xb + 2.0f) + v.w * (xb + 3.0f);
        pys += srow * yb;
    }

    float vals[13] = {pv[0], pv[1], pv[2], pv[3], pv[4], pv[5], pv[6], pv[7], pv[8], pv[9],
                      pt, pxs, pys};
#pragma unroll
    for (int k = 0; k < 13; ++k) {
        const float r = wred(vals[k]);
        if (lane == 0) red[wave][k] = r;
    }
    __syncthreads();
    if (tid < 13) {
        float s = 0.0f;
#pragma unroll
        for (int w = 0; w < 16; ++w) s += red[w][tid];
        pA[tid * 256 + b] = s;
    }
}

// ---- kB: xy-only LDS (2 blk/CU, 32 waves), samples; last block finishes ----
__global__ __launch_bounds__(1024, 8) void kB(const float* __restrict__ vertices,
                                              const int4*  __restrict__ tabS,
                                              const float4* __restrict__ tabW,
                                              const float* __restrict__ pA,
                                              float* __restrict__ pB,
                                              unsigned int* __restrict__ ctr,
                                              float* __restrict__ out) {
    const int bid  = blockIdx.x;
    const int b    = bid >> 1;
    const int half = bid & 1;
    const int tid  = threadIdx.x;
    const int wave = tid >> 6;
    const int lane = tid & 63;
    const int ln32 = tid & 31;

    __shared__ float2 sxy[NV];            // 55120 B
    __shared__ float  red[16][6];
    __shared__ float  ppvR[NPARTS * 32];
    __shared__ int    slast;

    const float* vb = vertices + (size_t)b * (NV * 3);
    for (int v = tid; v < NV; v += 1024)
        sxy[v] = make_float2(vb[3 * v], vb[3 * v + 1]);
    if (tid < NPARTS * 32) ppvR[tid] = pA[(tid >> 5) * 256 + b];
    __syncthreads();

    float cnx = 0.f, cny = 0.f, cd = 0.f;
    float pnx = 0.f, pny = 0.f, pd = 0.f;

    const int nbase = half * NHDH;
#pragma unroll 2
    for (int i = tid; i < NHDH; i += 1024) {      // exactly 10 iterations
        const int n = nbase + i;
        const int4   q = tabS[n];
        const float4 w = tabW[n];
        const float2 p0 = sxy[q.x];
        const float2 p1 = sxy[q.y];
        const float2 p2 = sxy[q.z];
        const float hx = w.x * p0.x + w.y * p1.x + w.z * p2.x;
        const float hy = w.x * p0.y + w.y * p1.y + w.z * p2.y;
        const float vol = ppvR[(q.w << 5) + ln32] * w.w;
        const float pw  = ((hy < 0.0f) ? (1.0f - 100.0f * hy) : __expf(-10.0f * hy)) * w.w;
        cnx += hx * vol; cny += hy * vol; cd += vol;
        pnx += hx * pw;  pny += hy * pw;  pd += pw;
    }

    float vals[6] = {cnx, cny, cd, pnx, pny, pd};
#pragma unroll
    for (int k = 0; k < 6; ++k) {
        const float r = wred(vals[k]);
        if (lane == 0) red[wave][k] = r;
    }
    __syncthreads();
    if (tid < 6) {
        float s = 0.0f;
#pragma unroll
        for (int w = 0; w < 16; ++w) s += red[w][tid];
        pB[tid * 512 + bid] = s;
    }
    __syncthreads();

    // ---- completion count; last block computes all outputs ----
    if (tid == 0) {
        __threadfence();                            // release pB
        const unsigned int prev = atomicAdd(ctr, 1u);
        slast = (prev == 2 * NB - 1) ? 1 : 0;
    }
    __syncthreads();
    if (!slast) return;
    __threadfence();                                // acquire side

    if (tid < NB) {
        const int bb = tid;
#define LD(P) __hip_atomic_load((P), __ATOMIC_RELAXED, __HIP_MEMORY_SCOPE_AGENT)
        const float fcnx = LD(&pB[0 * 512 + 2 * bb]) + LD(&pB[0 * 512 + 2 * bb + 1]);
        const float fcny = LD(&pB[1 * 512 + 2 * bb]) + LD(&pB[1 * 512 + 2 * bb + 1]);
        const float fcd  = LD(&pB[2 * 512 + 2 * bb]) + LD(&pB[2 * 512 + 2 * bb + 1]);
        const float fpnx = LD(&pB[3 * 512 + 2 * bb]) + LD(&pB[3 * 512 + 2 * bb + 1]);
        const float fpny = LD(&pB[4 * 512 + 2 * bb]) + LD(&pB[4 * 512 + 2 * bb + 1]);
        const float fpd  = LD(&pB[5 * 512 + 2 * bb]) + LD(&pB[5 * 512 + 2 * bb + 1]);
#undef LD
        const float pt  = pA[10 * 256 + bb];
        const float pxs = pA[11 * 256 + bb];
        const float pys = pA[12 * 256 + bb];

        const float comx  = fcnx / fcd;
        const float comy  = fcny / fcd;
        const float copx  = fpnx / (fpd + 1e-6f);
        const float copy_ = fpny / (fpd + 1e-6f);

        out[1 + 2 * bb + 0] = comx * 48.0f;
        out[1 + 2 * bb + 1] = (59.0f / 33.0f - comy) * 33.0f;
        out[1 + 2 * NB + 2 * bb + 0] = (copx + 18.0f / 78.74f) * (100.0f * 0.7874f);
        out[1 + 2 * NB + 2 * bb + 1] = (86.0f / 78.74f - copy_) * (100.0f * 0.7874f);

        const float total = (pt == 0.0f) ? 1e-8f : pt;
        const float xc = pxs / total;
        const float yc = pys / total;
        const float pcopx = 0.01f * (xc - 18.0f) / 0.7874f;
        const float pcopy = 0.01f * (86.0f - yc) / 0.7874f;

        const float dx = comx - pcopx;
        const float dy = comy - pcopy;
        float v = sqrtf(dx * dx + dy * dy);

        v = wred(v);
        if (lane == 0) red[wave][0] = v;
    }
    __syncthreads();
    if (tid == 0) {
        float s = 0.0f;
#pragma unroll
        for (int w = 0; w < 4; ++w) s += red[w][0];
        out[0] = s * (1.0f / NB);
    }
}

extern "C" void kernel_launch(void* const* d_in, const int* in_sizes, int n_in,
                              void* d_out, int out_size, void* d_ws, size_t ws_size,
                              hipStream_t stream) {
    const float* vertices    = (const float*)d_in[0];
    const float* pressure    = (const float*)d_in[1];
    const float* bary_w      = (const float*)d_in[2];
    const int*   faces       = (const int*)d_in[3];
    const int*   face_sample = (const int*)d_in[4];
    const int*   face_part   = (const int*)d_in[5];
    float* out = (float*)d_out;
    char*  wsb = (char*)d_ws;
    float* wsf = (float*)d_ws;

    unsigned int* ctr  = (unsigned int*)wsb;
    float*        pA   = wsf + PA_OFF;
    float*        pB   = wsf + PB_OFF;
    int4*         tabS = (int4*)(wsb + TABS_BYTE);
    float4*       tabW = (float4*)(wsb + TABW_BYTE);

    build_tabs<<<(NHDP + 255) / 256, 256, 0, stream>>>(faces, face_sample, face_part,
                                                       bary_w, tabS, tabW, ctr);
    kA<<<NB, 1024, 0, stream>>>(vertices, pressure, faces, face_part, pA);
    kB<<<NB * 2, 1024, 0, stream>>>(vertices, tabS, tabW, pA, pB, ctr, out);
}

// Round 8
// 43.691 us; speedup vs baseline: 2.5617x; 1.2968x over previous
//
#include <hip/hip_runtime.h>
#include <math.h>

#define NB 256
#define NV 6890
#define NF 13776
#define NHD 20000
#define NHDP 20480              // 20 iters x 1024 threads, mask-padded
#define NPARTS 10
#define PY 120
#define PX 40
#define THREADS 1024
#define NWAVES (THREADS / 64)

// ws layout (bytes):
//   [0,4)        ctr
//   [256,1280)   dist[NB]
//   [1280, +NHDP*16)  tabS int4{i0,i1,i2,part} (pads {0,0,0,0})
//   [..,  +NHDP*16)   tabW float4{w0,w1,w2,mask} (pads mask=0)
#define WS_CTR_OFF   0
#define WS_DIST_OFF  256
#define WS_TABS_OFF  1280
#define WS_TABW_OFF  (WS_TABS_OFF + NHDP * 16)
#define WS_NEEDED    (WS_TABW_OFF + NHDP * 16)

__device__ __forceinline__ float wred(float v) {
#pragma unroll
    for (int off = 32; off; off >>= 1) v += __shfl_down(v, off, 64);
    return v;
}

__global__ __launch_bounds__(256) void build_tabs(const int* __restrict__ faces,
                                                  const int* __restrict__ face_sample,
                                                  const int* __restrict__ face_part,
                                                  const float* __restrict__ bary_w,
                                                  int4* __restrict__ tabS,
                                                  float4* __restrict__ tabW,
                                                  unsigned int* __restrict__ ctr) {
    const int i = blockIdx.x * 256 + threadIdx.x;
    if (i == 0) *ctr = 0u;
    if (i < NHD) {
        const int fs = face_sample[i];
        tabS[i] = make_int4(faces[3 * fs + 0], faces[3 * fs + 1], faces[3 * fs + 2],
                            face_part[fs]);
        tabW[i] = make_float4(bary_w[3 * i + 0], bary_w[3 * i + 1], bary_w[3 * i + 2], 1.0f);
    } else if (i < NHDP) {
        tabS[i] = make_int4(0, 0, 0, 0);
        tabW[i] = make_float4(0.0f, 0.0f, 0.0f, 0.0f);
    }
}

__device__ __forceinline__ float tet_of(const float* __restrict__ svx,
                                        const float* __restrict__ svy,
                                        const float* __restrict__ svz, int4 q) {
    const float ax = svx[q.x], bx = svx[q.y], cx = svx[q.z];
    const float ay = svy[q.x], by = svy[q.y], cy = svy[q.z];
    const float az = svz[q.x], bz = svz[q.y], cz = svz[q.z];
    return (ax * (by * cz - bz * cy) + ay * (bz * cx - bx * cz) + az * (bx * cy - by * cx)) *
           (1.0f / 6.0f);
}

__global__ __launch_bounds__(THREADS, 4) void stab_main(
    const float* __restrict__ vertices,    // [NB, NV, 3]
    const float* __restrict__ pressure,    // [NB, PY, PX]
    const int*   __restrict__ faces,       // [NF, 3]
    const int*   __restrict__ face_part,   // [NF]
    const int4*  __restrict__ tabS,
    const float4* __restrict__ tabW,
    float* __restrict__ out,
    float* __restrict__ dist,
    unsigned int* __restrict__ ctr)
{
    const int b    = blockIdx.x;
    const int tid  = threadIdx.x;
    const int wave = tid >> 6;
    const int lane = tid & 63;
    const int ln32 = tid & 31;

    __shared__ float svx[NV];
    __shared__ float svy[NV];
    __shared__ float svz[NV];
    __shared__ float red[NWAVES][13];
    __shared__ float ppvR[NPARTS * 32];   // replicated per 32-lane group: conflict-free
    __shared__ int   slast;

    // ---- pressure moments first: HBM loads issue under LDS staging ----
    float pt = 0.f, pxs = 0.f, pys = 0.f;
    {
        const float4* pb4 = (const float4*)(pressure + (size_t)b * (PY * PX));
#pragma unroll
        for (int k = 0; k < 2; ++k) {
            const int i = tid + k * THREADS;
            if (i < (PY * PX) / 4) {
                const float4 v = pb4[i];
                const int idx = 4 * i;
                const float xb = (float)(idx % PX);
                const float yb = (float)(idx / PX);
                const float srow = v.x + v.y + v.z + v.w;
                pt  += srow;
                pxs += v.x * xb + v.y * (xb + 1.0f) + v.z * (xb + 2.0f) + v.w * (xb + 3.0f);
                pys += srow * yb;
            }
        }
    }

    // ---- stage vertices[b] into LDS (f32 SoA) ----
    const float* vb = vertices + (size_t)b * (NV * 3);
    for (int v = tid; v < NV; v += THREADS) {
        svx[v] = vb[3 * v + 0];
        svy[v] = vb[3 * v + 1];
        svz[v] = vb[3 * v + 2];
    }
    __syncthreads();

    // ---- Phase A: tet volumes -> per-part sums (4 independent chains / iter) ----
    float pv[NPARTS];
#pragma unroll
    for (int p = 0; p < NPARTS; ++p) pv[p] = 0.0f;

    for (int f0 = tid; f0 < NF; f0 += 4 * THREADS) {
        const int f1 = f0 + THREADS, f2 = f0 + 2 * THREADS, f3 = f0 + 3 * THREADS;
        const int g1 = min(f1, NF - 1), g2 = min(f2, NF - 1), g3 = min(f3, NF - 1);
        const int4 q0 = make_int4(faces[3 * f0], faces[3 * f0 + 1], faces[3 * f0 + 2],
                                  face_part[f0]);
        const int4 q1 = make_int4(faces[3 * g1], faces[3 * g1 + 1], faces[3 * g1 + 2],
                                  face_part[g1]);
        const int4 q2 = make_int4(faces[3 * g2], faces[3 * g2 + 1], faces[3 * g2 + 2],
                                  face_part[g2]);
        const int4 q3 = make_int4(faces[3 * g3], faces[3 * g3 + 1], faces[3 * g3 + 2],
                                  face_part[g3]);
        const float m1 = (f1 < NF) ? 1.0f : 0.0f;
        const float m2 = (f2 < NF) ? 1.0f : 0.0f;
        const float m3 = (f3 < NF) ? 1.0f : 0.0f;
        const float t0 = tet_of(svx, svy, svz, q0);
        const float t1 = tet_of(svx, svy, svz, q1) * m1;
        const float t2 = tet_of(svx, svy, svz, q2) * m2;
        const float t3 = tet_of(svx, svy, svz, q3) * m3;
#pragma unroll
        for (int p = 0; p < NPARTS; ++p) {
            pv[p] += (q0.w == p) ? t0 : 0.0f;
            pv[p] += (q1.w == p) ? t1 : 0.0f;
            pv[p] += (q2.w == p) ? t2 : 0.0f;
            pv[p] += (q3.w == p) ? t3 : 0.0f;
        }
    }

#pragma unroll
    for (int p = 0; p < NPARTS; ++p) {
        const float r = wred(pv[p]);
        if (lane == 0) red[wave][p] = r;
    }
    __syncthreads();
    if (tid < NPARTS * 32) {
        const int p = tid >> 5;
        float s = 0.0f;
#pragma unroll
        for (int w = 0; w < NWAVES; ++w) s += red[w][p];
        ppvR[tid] = s;
    }
    __syncthreads();

    // ---- Phase B: blended samples; fixed 20 iters, compiler-unrolled x4 ----
    float cnx = 0.f, cny = 0.f, cd = 0.f;
    float pnx = 0.f, pny = 0.f, pd = 0.f;

#pragma unroll 4
    for (int k = 0; k < NHDP / THREADS; ++k) {
        const int n = tid + k * THREADS;
        const int4   q = tabS[n];
        const float4 w = tabW[n];
        const float hx = w.x * svx[q.x] + w.y * svx[q.y] + w.z * svx[q.z];
        const float hy = w.x * svy[q.x] + w.y * svy[q.y] + w.z * svy[q.z];
        const float vol = ppvR[(q.w << 5) + ln32] * w.w;
        const float pw  = ((hy < 0.0f) ? (1.0f - 100.0f * hy) : __expf(-10.0f * hy)) * w.w;
        cnx += hx * vol; cny += hy * vol; cd += vol;
        pnx += hx * pw;  pny += hy * pw;  pd += pw;
    }

    // ---- block reduction of 9 scalars ----
    float vals[9] = {cnx, cny, cd, pnx, pny, pd, pt, pxs, pys};
#pragma unroll
    for (int k = 0; k < 9; ++k) {
        const float r = wred(vals[k]);
        if (lane == 0) red[wave][k] = r;
    }
    __syncthreads();

    if (tid == 0) {
        float s[9];
#pragma unroll
        for (int k = 0; k < 9; ++k) {
            float acc = 0.0f;
#pragma unroll
            for (int w = 0; w < NWAVES; ++w) acc += red[w][k];
            s[k] = acc;
        }
        const float comx  = s[0] / s[2];
        const float comy  = s[1] / s[2];
        const float copx  = s[3] / (s[5] + 1e-6f);
        const float copy_ = s[4] / (s[5] + 1e-6f);

        out[1 + 2 * b + 0] = comx * 48.0f;
        out[1 + 2 * b + 1] = (59.0f / 33.0f - comy) * 33.0f;
        out[1 + 2 * NB + 2 * b + 0] = (copx + 18.0f / 78.74f) * (100.0f * 0.7874f);
        out[1 + 2 * NB + 2 * b + 1] = (86.0f / 78.74f - copy_) * (100.0f * 0.7874f);

        const float total = (s[6] == 0.0f) ? 1e-8f : s[6];
        const float xc = s[7] / total;
        const float yc = s[8] / total;
        const float pcopx = 0.01f * (xc - 18.0f) / 0.7874f;
        const float pcopy = 0.01f * (86.0f - yc) / 0.7874f;

        const float dx = comx - pcopx;
        const float dy = comy - pcopy;
        dist[b] = sqrtf(dx * dx + dy * dy);
    }

    // ---- fused final reduce: last block sums dist[] ----
    if (tid == 0) {
        __threadfence();                          // release dist[b]
        const unsigned int prev = atomicAdd(ctr, 1u);
        slast = (prev == NB - 1) ? 1 : 0;
    }
    __syncthreads();
    if (!slast) return;
    __threadfence();                              // acquire

    float v = 0.0f;
    if (tid < NB)
        v = __hip_atomic_load(&dist[tid], __ATOMIC_RELAXED, __HIP_MEMORY_SCOPE_AGENT);
    v = wred(v);
    if (lane == 0) red[wave][0] = v;
    __syncthreads();
    if (tid == 0) {
        float s = 0.0f;
#pragma unroll
        for (int w = 0; w < 4; ++w) s += red[w][0];   // only waves 0-3 hold dist
        out[0] = s * (1.0f / NB);
    }
}

extern "C" void kernel_launch(void* const* d_in, const int* in_sizes, int n_in,
                              void* d_out, int out_size, void* d_ws, size_t ws_size,
                              hipStream_t stream) {
    const float* vertices    = (const float*)d_in[0];
    const float* pressure    = (const float*)d_in[1];
    const float* bary_w      = (const float*)d_in[2];
    const int*   faces       = (const int*)d_in[3];
    const int*   face_sample = (const int*)d_in[4];
    const int*   face_part   = (const int*)d_in[5];
    float* out = (float*)d_out;
    char*  wsb = (char*)d_ws;

    unsigned int* ctr  = (unsigned int*)(wsb + WS_CTR_OFF);
    float*        dist = (float*)(wsb + WS_DIST_OFF);
    int4*         tabS = (int4*)(wsb + WS_TABS_OFF);
    float4*       tabW = (float4*)(wsb + WS_TABW_OFF);

    build_tabs<<<(NHDP + 255) / 256, 256, 0, stream>>>(faces, face_sample, face_part,
                                                       bary_w, tabS, tabW, ctr);
    stab_main<<<NB, THREADS, 0, stream>>>(vertices, pressure, faces, face_part,
                                          tabS, tabW, out, dist, ctr);
}